// Round 4
// baseline (310.833 us; speedup 1.0000x reference)
//
#include <hip/hip_runtime.h>
#include <cstdint>

#define DIMC 1024
#define NSEQ 2048
#define BATCH 2
#define HEADS 16
#define HD 64
#define MROWS (BATCH * NSEQ) /* 4096 */

typedef unsigned short u16;
typedef unsigned int u32;
typedef __attribute__((ext_vector_type(8))) short bf16x8;
typedef __attribute__((ext_vector_type(4))) float f32x4;

#if __has_builtin(__builtin_amdgcn_exp2f)
#define EXP2(x) __builtin_amdgcn_exp2f(x)
#else
#define EXP2(x) exp2f(x)
#endif

__device__ __forceinline__ u16 f2bf(float f) {
  union { float f; u32 u; } v; v.f = f;
  u32 u = v.u;
  return (u16)((u + 0x7fffu + ((u >> 16) & 1u)) >> 16);
}
__device__ __forceinline__ u32 pack_rne(float a, float b) {
  return (u32)f2bf(a) | ((u32)f2bf(b) << 16);
}
__device__ __forceinline__ u32 pack_trunc(float a, float b) {
  union { float f; u32 u; } x, y; x.f = a; y.f = b;
  return (x.u >> 16) | (y.u & 0xffff0000u);
}
// async global->LDS, 16B per lane. LDS dest must be wave-uniform base + lane*16.
__device__ __forceinline__ void gload_lds16(const void* g, void* l) {
  __builtin_amdgcn_global_load_lds((const __attribute__((address_space(1))) void*)g,
                                   (__attribute__((address_space(3))) void*)l, 16, 0, 0);
}

// ---------------- prep: LayerNorm+cast (blocks 0..12287) & W transpose+cast ----
__global__ __launch_bounds__(256)
void prep(const float* __restrict__ q, const float* __restrict__ k,
          const float* __restrict__ v,
          const float* __restrict__ gq, const float* __restrict__ bq,
          const float* __restrict__ gk, const float* __restrict__ bk,
          const float* __restrict__ gv, const float* __restrict__ bv,
          const float* __restrict__ w0, const float* __restrict__ w1,
          const float* __restrict__ w2, const float* __restrict__ w3,
          u16* __restrict__ xn, u16* __restrict__ wtout) {
  __shared__ float rs[4], rs2[4];
  __shared__ float tile[32][33];
  int tid = threadIdx.x;
  if (blockIdx.x < 3 * MROWS) {
    int rowid = blockIdx.x;
    int tensor = rowid >> 12;
    int r = rowid & 4095;
    const float *src, *g, *b;
    if (tensor == 0)      { src = q; g = gq; b = bq; }
    else if (tensor == 1) { src = k; g = gk; b = bk; }
    else                  { src = v; g = gv; b = bv; }
    src += (size_t)r * DIMC;
    u16* dst = xn + (size_t)tensor * MROWS * DIMC + (size_t)r * DIMC;
    float4 x = ((const float4*)src)[tid];
    float s  = x.x + x.y + x.z + x.w;
    float s2 = x.x*x.x + x.y*x.y + x.z*x.z + x.w*x.w;
    #pragma unroll
    for (int m = 1; m < 64; m <<= 1) { s += __shfl_xor(s, m); s2 += __shfl_xor(s2, m); }
    int wave = tid >> 6, lane = tid & 63;
    if (lane == 0) { rs[wave] = s; rs2[wave] = s2; }
    __syncthreads();
    s  = rs[0] + rs[1] + rs[2] + rs[3];
    s2 = rs2[0] + rs2[1] + rs2[2] + rs2[3];
    float mu  = s * (1.0f / DIMC);
    float var = s2 * (1.0f / DIMC) - mu * mu;
    float inv = rsqrtf(var + 1e-5f);
    float4 gg = ((const float4*)g)[tid];
    float4 bb = ((const float4*)b)[tid];
    uint2 o;
    o.x = pack_rne((x.x - mu) * inv * gg.x + bb.x, (x.y - mu) * inv * gg.y + bb.y);
    o.y = pack_rne((x.z - mu) * inv * gg.z + bb.z, (x.w - mu) * inv * gg.w + bb.w);
    ((uint2*)dst)[tid] = o;
  } else {
    int blk = blockIdx.x - 3 * MROWS;
    int widx = blk >> 10, t = blk & 1023;
    int ti = t >> 5, tj = t & 31;
    const float* W = (widx == 0) ? w0 : (widx == 1) ? w1 : (widx == 2) ? w2 : w3;
    u16* O = wtout + (size_t)widx * DIMC * DIMC;
    int tx = tid & 31, ty = tid >> 5;
    #pragma unroll
    for (int rr = 0; rr < 32; rr += 8)
      tile[ty + rr][tx] = W[(size_t)(ti * 32 + ty + rr) * DIMC + tj * 32 + tx];
    __syncthreads();
    #pragma unroll
    for (int rr = 0; rr < 32; rr += 8)
      O[(size_t)(tj * 32 + ty + rr) * DIMC + ti * 32 + tx] = f2bf(tile[tx][ty + rr]);
  }
}

// ---------------- fused QKV projection GEMM (grid.z selects Q/K/V) ----------------
// z==2 epilogue also produces V^T [bh][d][n] via LDS transpose (padded stride 136).
__global__ __launch_bounds__(256)
void qkv_gemm(const u16* __restrict__ xn, const u16* __restrict__ wt,
              const float* __restrict__ bq, const float* __restrict__ bk,
              const float* __restrict__ bv,
              float* __restrict__ out, u16* __restrict__ qh,
              u16* __restrict__ khb, u16* __restrict__ vtb) {
  __shared__ u16 smem[128 * 136];           // 34.8 KB; front 16 KB doubles as As/Bs
  u16* As = smem;                            // 128*32
  u16* Bs = smem + 4096;                     // 128*32
  u16* Ls = smem;                            // transpose tile [c][m] stride 136
  const int z = blockIdx.z;
  const u16* A  = xn + (size_t)z * MROWS * DIMC;
  const u16* Bt = wt + (size_t)z * DIMC * DIMC;
  const float* bias = (z == 0) ? bq : (z == 1) ? bk : bv;
  const int bm = blockIdx.x, bn = blockIdx.y;
  const int tid = threadIdx.x;
  const int wave = tid >> 6, lane = tid & 63;
  const int wm = (wave & 1) * 64, wn = (wave >> 1) * 64;
  const int row = lane & 15, quad = lane >> 4;
  const float QSCL = 0.18033688011112042f;  // 0.125 * log2(e)
  f32x4 acc[4][4] = {};
  for (int k0 = 0; k0 < DIMC; k0 += 32) {
    #pragma unroll
    for (int c = 0; c < 2; ++c) {
      int e = c * 2048 + tid * 8;
      int rr = e >> 5, col = e & 31;
      gload_lds16(&A[(size_t)(bm * 128 + rr) * DIMC + k0 + col], &As[e]);
      gload_lds16(&Bt[(size_t)(bn * 128 + rr) * DIMC + k0 + col], &Bs[e]);
    }
    __syncthreads();
    bf16x8 a[4], b[4];
    #pragma unroll
    for (int i = 0; i < 4; ++i)
      a[i] = *(const bf16x8*)(&As[(wm + i * 16 + row) * 32 + quad * 8]);
    #pragma unroll
    for (int j = 0; j < 4; ++j)
      b[j] = *(const bf16x8*)(&Bs[(wn + j * 16 + row) * 32 + quad * 8]);
    #pragma unroll
    for (int i = 0; i < 4; ++i)
      #pragma unroll
      for (int j = 0; j < 4; ++j)
        acc[i][j] = __builtin_amdgcn_mfma_f32_16x16x32_bf16(a[i], b[j], acc[i][j], 0, 0, 0);
    __syncthreads();
  }
  #pragma unroll
  for (int i = 0; i < 4; ++i) {
    #pragma unroll
    for (int j = 0; j < 4; ++j) {
      float val[4];
      #pragma unroll
      for (int r = 0; r < 4; ++r) {
        int m = bm * 128 + wm + i * 16 + quad * 4 + r;
        int c = bn * 128 + wn + j * 16 + row;
        val[r] = acc[i][j][r] + bias[c];
        int b_ = m >> 11, n = m & 2047, h = c >> 6, d = c & 63;
        int bh = b_ * HEADS + h;
        size_t hidx = ((size_t)bh * NSEQ + n) * HD + d;
        if (z == 0) {
          qh[hidx] = f2bf(val[r] * QSCL);   // pre-scaled for attention exp2
        } else {
          out[(size_t)z * MROWS * DIMC + hidx] = val[r];
          if (z == 1) khb[hidx] = f2bf(val[r]);
        }
      }
      if (z == 2) {
        int ct = wn + j * 16 + row;
        int mt = wm + i * 16 + quad * 4;
        u32* L = (u32*)(&Ls[ct * 136 + mt]);
        L[0] = pack_rne(val[0], val[1]);
        L[1] = pack_rne(val[2], val[3]);
      }
    }
  }
  if (z == 2) {
    __syncthreads();
    int b_ = (bm * 128) >> 11;
    int nbase = (bm * 128) & 2047;
    #pragma unroll
    for (int it = 0; it < 8; ++it) {
      int idx = it * 256 + tid;
      int ct = idx >> 4, ch = idx & 15;     // ct = c within tile, ch = 8-m chunk
      uint4 y = *(const uint4*)(&Ls[ct * 136 + ch * 8]);
      int c = bn * 128 + ct;
      int h = c >> 6, d = c & 63;
      size_t o = ((size_t)(b_ * HEADS + h) * HD + d) * NSEQ + nbase + ch * 8;
      *(uint4*)(&vtb[o]) = y;
    }
  }
}

// ---------------- output projection GEMM (64x128 tile, fp32 row-major out) ------
__global__ __launch_bounds__(256)
void out_gemm(const u16* __restrict__ A, const u16* __restrict__ Bt,
              const float* __restrict__ bias, float* __restrict__ outf) {
  __shared__ u16 As[64 * 32];
  __shared__ u16 Bs[128 * 32];
  const int bm = blockIdx.x, bn = blockIdx.y;
  const int tid = threadIdx.x;
  const int wave = tid >> 6, lane = tid & 63;
  const int wm = (wave & 1) * 32, wn = (wave >> 1) * 64;
  const int row = lane & 15, quad = lane >> 4;
  f32x4 acc[2][4] = {};
  for (int k0 = 0; k0 < DIMC; k0 += 32) {
    {
      int e = tid * 8;
      int rr = e >> 5, col = e & 31;
      gload_lds16(&A[(size_t)(bm * 64 + rr) * DIMC + k0 + col], &As[e]);
    }
    #pragma unroll
    for (int c = 0; c < 2; ++c) {
      int e = c * 2048 + tid * 8;
      int rr = e >> 5, col = e & 31;
      gload_lds16(&Bt[(size_t)(bn * 128 + rr) * DIMC + k0 + col], &Bs[e]);
    }
    __syncthreads();
    bf16x8 a[2], b[4];
    #pragma unroll
    for (int i = 0; i < 2; ++i)
      a[i] = *(const bf16x8*)(&As[(wm + i * 16 + row) * 32 + quad * 8]);
    #pragma unroll
    for (int j = 0; j < 4; ++j)
      b[j] = *(const bf16x8*)(&Bs[(wn + j * 16 + row) * 32 + quad * 8]);
    #pragma unroll
    for (int i = 0; i < 2; ++i)
      #pragma unroll
      for (int j = 0; j < 4; ++j)
        acc[i][j] = __builtin_amdgcn_mfma_f32_16x16x32_bf16(a[i], b[j], acc[i][j], 0, 0, 0);
    __syncthreads();
  }
  #pragma unroll
  for (int i = 0; i < 2; ++i)
    #pragma unroll
    for (int j = 0; j < 4; ++j)
      #pragma unroll
      for (int r = 0; r < 4; ++r) {
        int m = bm * 64 + wm + i * 16 + quad * 4 + r;
        int c = bn * 128 + wn + j * 16 + row;
        outf[(size_t)m * DIMC + c] = acc[i][j][r] + bias[c];
      }
}

// ---------------- fused flash attention (128-q blocks, 32 q-rows per wave) ------
// DIRECT-GLOBAL operand fetch: every K/V fragment is a 16B contiguous run in
// global (kh row-major [key][d]; vtb [d][key] contiguous in key), and R2's XCD
// clustering made the per-XCD working set 2MB (L2-resident, FETCH=12MB proved
// it). So fragments load global->VGPR via dwordx4 — no LDS staging, no
// double-buffer, NO __syncthreads at all. Software-pipelined one 32-key unit
// ahead with named A/B register sets (counted vmcnt keeps 8 loads in flight
// under compute). DS pipe now carries only the Ps round-trip. All 4 waves of a
// block read the same K/V lines -> L1 hits. Compute body verbatim R3.
__global__ __launch_bounds__(256)
void attn_fused(const u16* __restrict__ qh, const u16* __restrict__ kh,
                const u16* __restrict__ vt, u16* __restrict__ ao) {
  __shared__ u16 Ps[4][2][16 * 40];  // per wave, per q-subtile [q][32key] stride 40
  const int flat = blockIdx.x;
  const int bh = (flat & 7) * 4 + ((flat >> 3) & 3);
  const int qtile = flat >> 5;       // 0..15, 128 q-rows each
  const int b = bh >> 4, h = bh & 15;
  const int tid = threadIdx.x;
  const int wave = tid >> 6, lane = tid & 63;
  const int qi = lane & 15, quad = lane >> 4;
  const size_t base = (size_t)bh * NSEQ * HD;
  bf16x8 qf[2][2];                   // [q-subtile][d-half]
  #pragma unroll
  for (int qt = 0; qt < 2; ++qt) {
    int qrow = qtile * 128 + wave * 32 + qt * 16 + qi;
    #pragma unroll
    for (int dh = 0; dh < 2; ++dh)
      qf[qt][dh] = *(const bf16x8*)(&qh[base + (size_t)qrow * HD + dh * 32 + quad * 8]);
  }
  // per-lane global cursors (advance per 32-key unit)
  const u16* kp  = kh + base + qi * HD + quad * 8;            // K[key][d]
  const u16* vp0 = vt + base + (size_t)qi * NSEQ + quad * 8;  // V^T[d][key]
  const u16* vp1 = vp0 + 16 * NSEQ;
  const u16* vp2 = vp0 + 32 * NSEQ;
  const u16* vp3 = vp0 + 48 * NSEQ;
  float li0 = 0.f, li1 = 0.f;
  f32x4 oacc[2][4] = {};
  u16* P0 = &Ps[wave][0][0];
  u16* P1 = &Ps[wave][1][0];
  bf16x8 k0A, k1A, k2A, k3A, v0A, v1A, v2A, v3A;
  bf16x8 k0B, k1B, k2B, k3B, v0B, v1B, v2B, v3B;

#define ALOADF(S) do {                          \
    k0##S = *(const bf16x8*)(kp);               \
    k1##S = *(const bf16x8*)(kp + 32);          \
    k2##S = *(const bf16x8*)(kp + 1024);        \
    k3##S = *(const bf16x8*)(kp + 1056);        \
    v0##S = *(const bf16x8*)(vp0);              \
    v1##S = *(const bf16x8*)(vp1);              \
    v2##S = *(const bf16x8*)(vp2);              \
    v3##S = *(const bf16x8*)(vp3);              \
    kp += 32 * HD; vp0 += 32; vp1 += 32; vp2 += 32; vp3 += 32; \
  } while (0)

#define AUNIT(S) do {                                                                  \
    f32x4 s00 = {}, s01 = {}, s10 = {}, s11 = {};                                      \
    __builtin_amdgcn_s_setprio(1);                                                     \
    s00 = __builtin_amdgcn_mfma_f32_16x16x32_bf16(k0##S, qf[0][0], s00, 0, 0, 0);      \
    s00 = __builtin_amdgcn_mfma_f32_16x16x32_bf16(k1##S, qf[0][1], s00, 0, 0, 0);      \
    s01 = __builtin_amdgcn_mfma_f32_16x16x32_bf16(k2##S, qf[0][0], s01, 0, 0, 0);      \
    s01 = __builtin_amdgcn_mfma_f32_16x16x32_bf16(k3##S, qf[0][1], s01, 0, 0, 0);      \
    s10 = __builtin_amdgcn_mfma_f32_16x16x32_bf16(k0##S, qf[1][0], s10, 0, 0, 0);      \
    s10 = __builtin_amdgcn_mfma_f32_16x16x32_bf16(k1##S, qf[1][1], s10, 0, 0, 0);      \
    s11 = __builtin_amdgcn_mfma_f32_16x16x32_bf16(k2##S, qf[1][0], s11, 0, 0, 0);      \
    s11 = __builtin_amdgcn_mfma_f32_16x16x32_bf16(k3##S, qf[1][1], s11, 0, 0, 0);      \
    __builtin_amdgcn_s_setprio(0);                                                     \
    float a0 = EXP2(s00[0]), a1 = EXP2(s00[1]), a2 = EXP2(s00[2]), a3 = EXP2(s00[3]);  \
    float a4 = EXP2(s01[0]), a5 = EXP2(s01[1]), a6 = EXP2(s01[2]), a7 = EXP2(s01[3]);  \
    float b0 = EXP2(s10[0]), b1 = EXP2(s10[1]), b2 = EXP2(s10[2]), b3 = EXP2(s10[3]);  \
    float b4 = EXP2(s11[0]), b5 = EXP2(s11[1]), b6 = EXP2(s11[2]), b7 = EXP2(s11[3]);  \
    li0 += ((a0 + a1) + (a2 + a3)) + ((a4 + a5) + (a6 + a7));                          \
    li1 += ((b0 + b1) + (b2 + b3)) + ((b4 + b5) + (b6 + b7));                          \
    {                                                                                  \
      uint2 w;                                                                         \
      w.x = pack_trunc(a0, a1); w.y = pack_trunc(a2, a3);                              \
      *(uint2*)(&P0[qi * 40 + quad * 4]) = w;                                          \
      w.x = pack_trunc(a4, a5); w.y = pack_trunc(a6, a7);                              \
      *(uint2*)(&P0[qi * 40 + 16 + quad * 4]) = w;                                     \
      w.x = pack_trunc(b0, b1); w.y = pack_trunc(b2, b3);                              \
      *(uint2*)(&P1[qi * 40 + quad * 4]) = w;                                          \
      w.x = pack_trunc(b4, b5); w.y = pack_trunc(b6, b7);                              \
      *(uint2*)(&P1[qi * 40 + 16 + quad * 4]) = w;                                     \
    }                                                                                  \
    asm volatile("" ::: "memory");  /* order Ps writes before reads (same wave) */     \
    bf16x8 pf0 = *(const bf16x8*)(&P0[qi * 40 + quad * 8]);                            \
    bf16x8 pf1 = *(const bf16x8*)(&P1[qi * 40 + quad * 8]);                            \
    __builtin_amdgcn_s_setprio(1);                                                     \
    oacc[0][0] = __builtin_amdgcn_mfma_f32_16x16x32_bf16(v0##S, pf0, oacc[0][0], 0, 0, 0); \
    oacc[1][0] = __builtin_amdgcn_mfma_f32_16x16x32_bf16(v0##S, pf1, oacc[1][0], 0, 0, 0); \
    oacc[0][1] = __builtin_amdgcn_mfma_f32_16x16x32_bf16(v1##S, pf0, oacc[0][1], 0, 0, 0); \
    oacc[1][1] = __builtin_amdgcn_mfma_f32_16x16x32_bf16(v1##S, pf1, oacc[1][1], 0, 0, 0); \
    oacc[0][2] = __builtin_amdgcn_mfma_f32_16x16x32_bf16(v2##S, pf0, oacc[0][2], 0, 0, 0); \
    oacc[1][2] = __builtin_amdgcn_mfma_f32_16x16x32_bf16(v2##S, pf1, oacc[1][2], 0, 0, 0); \
    oacc[0][3] = __builtin_amdgcn_mfma_f32_16x16x32_bf16(v3##S, pf0, oacc[0][3], 0, 0, 0); \
    oacc[1][3] = __builtin_amdgcn_mfma_f32_16x16x32_bf16(v3##S, pf1, oacc[1][3], 0, 0, 0); \
    __builtin_amdgcn_s_setprio(0);                                                     \
  } while (0)

  ALOADF(A);                       // unit 0
  for (int u = 0; u < NSEQ / 32; u += 2) {
    ALOADF(B);                     // prefetch unit u+1 (u+1 <= 63 always)
    AUNIT(A);                      // compute unit u
    if (u + 2 < NSEQ / 32) ALOADF(A);  // prefetch unit u+2
    AUNIT(B);                      // compute unit u+1
  }
#undef ALOADF
#undef AUNIT

  // deferred cross-lane softmax-denominator reduction (once, not per chunk)
  li0 += __shfl_xor(li0, 16); li0 += __shfl_xor(li0, 32);
  li1 += __shfl_xor(li1, 16); li1 += __shfl_xor(li1, 32);
  #pragma unroll
  for (int qt = 0; qt < 2; ++qt) {
    float inv = 1.0f / (qt == 0 ? li0 : li1);
    int token = b * NSEQ + qtile * 128 + wave * 32 + qt * 16 + qi;
    #pragma unroll
    for (int dt = 0; dt < 4; ++dt) {
      int col = h * 64 + dt * 16 + quad * 4;
      *(u32*)(&ao[(size_t)token * DIMC + col]) =
          pack_rne(oacc[qt][dt][0] * inv, oacc[qt][dt][1] * inv);
      *(u32*)(&ao[(size_t)token * DIMC + col + 2]) =
          pack_rne(oacc[qt][dt][2] * inv, oacc[qt][dt][3] * inv);
    }
  }
}

extern "C" void kernel_launch(void* const* d_in, const int* in_sizes, int n_in,
                              void* d_out, int out_size, void* d_ws, size_t ws_size,
                              hipStream_t stream) {
  const float* q    = (const float*)d_in[0];
  const float* k    = (const float*)d_in[1];
  const float* v    = (const float*)d_in[2];
  const float* gq   = (const float*)d_in[3];
  const float* bqln = (const float*)d_in[4];
  const float* gk   = (const float*)d_in[5];
  const float* bkln = (const float*)d_in[6];
  const float* gv   = (const float*)d_in[7];
  const float* bvln = (const float*)d_in[8];
  const float* Wq   = (const float*)d_in[9];
  const float* bq   = (const float*)d_in[10];
  const float* Wk   = (const float*)d_in[11];
  const float* bk   = (const float*)d_in[12];
  const float* Wv   = (const float*)d_in[13];
  const float* bv   = (const float*)d_in[14];
  const float* Wp   = (const float*)d_in[15];
  const float* bp   = (const float*)d_in[16];
  float* out = (float*)d_out;

  char* ws = (char*)d_ws;
  u16* xn  = (u16*)(ws);                          // 3 x 4096x1024 bf16 (24MB)
  u16* wt  = (u16*)(ws + (size_t)25165824);       // 4 x 1024x1024 bf16 (8MB)
  u16* qh  = (u16*)(ws + (size_t)33554432);       // [bh][n][d] bf16 (pre-scaled)
  u16* khb = (u16*)(ws + (size_t)41943040);       // [bh][n][d] bf16
  u16* ao  = (u16*)(ws + (size_t)50331648);       // [token][1024] bf16
  // V^T lives in the output-0 region of d_out (16.78 MB, exactly fits);
  // out_gemm overwrites it afterwards.
  u16* vtb = (u16*)d_out;                         // [bh][d][n] bf16

  const size_t WEL = (size_t)DIMC * DIMC;

  prep<<<3 * MROWS + 4096, 256, 0, stream>>>(q, k, v, gq, bqln, gk, bkln, gv, bvln,
                                             Wq, Wk, Wv, Wp, xn, wt);
  qkv_gemm<<<dim3(MROWS / 128, DIMC / 128, 3), 256, 0, stream>>>(
      xn, wt, bq, bk, bv, out, qh, khb, vtb);
  attn_fused<<<dim3((NSEQ / 128) * BATCH * HEADS), 256, 0, stream>>>(qh, khb, vtb, ao);
  out_gemm<<<dim3(MROWS / 64, DIMC / 128), 256, 0, stream>>>(ao, wt + 3 * WEL, bp, out);
}

// Round 5
// 241.343 us; speedup vs baseline: 1.2879x; 1.2879x over previous
//
#include <hip/hip_runtime.h>
#include <cstdint>

#define DIMC 1024
#define NSEQ 2048
#define BATCH 2
#define HEADS 16
#define HD 64
#define MROWS (BATCH * NSEQ) /* 4096 */

typedef unsigned short u16;
typedef unsigned int u32;
typedef __attribute__((ext_vector_type(8))) short bf16x8;
typedef __attribute__((ext_vector_type(4))) float f32x4;

#if __has_builtin(__builtin_amdgcn_exp2f)
#define EXP2(x) __builtin_amdgcn_exp2f(x)
#else
#define EXP2(x) exp2f(x)
#endif

__device__ __forceinline__ u16 f2bf(float f) {
  union { float f; u32 u; } v; v.f = f;
  u32 u = v.u;
  return (u16)((u + 0x7fffu + ((u >> 16) & 1u)) >> 16);
}
__device__ __forceinline__ u32 pack_rne(float a, float b) {
  return (u32)f2bf(a) | ((u32)f2bf(b) << 16);
}
__device__ __forceinline__ u32 pack_trunc(float a, float b) {
  union { float f; u32 u; } x, y; x.f = a; y.f = b;
  return (x.u >> 16) | (y.u & 0xffff0000u);
}
// async global->LDS, 16B per lane. LDS dest must be wave-uniform base + lane*16.
__device__ __forceinline__ void gload_lds16(const void* g, void* l) {
  __builtin_amdgcn_global_load_lds((const __attribute__((address_space(1))) void*)g,
                                   (__attribute__((address_space(3))) void*)l, 16, 0, 0);
}

// ---------------- prep: LayerNorm+cast (blocks 0..12287) & W transpose+cast ----
__global__ __launch_bounds__(256)
void prep(const float* __restrict__ q, const float* __restrict__ k,
          const float* __restrict__ v,
          const float* __restrict__ gq, const float* __restrict__ bq,
          const float* __restrict__ gk, const float* __restrict__ bk,
          const float* __restrict__ gv, const float* __restrict__ bv,
          const float* __restrict__ w0, const float* __restrict__ w1,
          const float* __restrict__ w2, const float* __restrict__ w3,
          u16* __restrict__ xn, u16* __restrict__ wtout) {
  __shared__ float rs[4], rs2[4];
  __shared__ float tile[32][33];
  int tid = threadIdx.x;
  if (blockIdx.x < 3 * MROWS) {
    int rowid = blockIdx.x;
    int tensor = rowid >> 12;
    int r = rowid & 4095;
    const float *src, *g, *b;
    if (tensor == 0)      { src = q; g = gq; b = bq; }
    else if (tensor == 1) { src = k; g = gk; b = bk; }
    else                  { src = v; g = gv; b = bv; }
    src += (size_t)r * DIMC;
    u16* dst = xn + (size_t)tensor * MROWS * DIMC + (size_t)r * DIMC;
    float4 x = ((const float4*)src)[tid];
    float s  = x.x + x.y + x.z + x.w;
    float s2 = x.x*x.x + x.y*x.y + x.z*x.z + x.w*x.w;
    #pragma unroll
    for (int m = 1; m < 64; m <<= 1) { s += __shfl_xor(s, m); s2 += __shfl_xor(s2, m); }
    int wave = tid >> 6, lane = tid & 63;
    if (lane == 0) { rs[wave] = s; rs2[wave] = s2; }
    __syncthreads();
    s  = rs[0] + rs[1] + rs[2] + rs[3];
    s2 = rs2[0] + rs2[1] + rs2[2] + rs2[3];
    float mu  = s * (1.0f / DIMC);
    float var = s2 * (1.0f / DIMC) - mu * mu;
    float inv = rsqrtf(var + 1e-5f);
    float4 gg = ((const float4*)g)[tid];
    float4 bb = ((const float4*)b)[tid];
    uint2 o;
    o.x = pack_rne((x.x - mu) * inv * gg.x + bb.x, (x.y - mu) * inv * gg.y + bb.y);
    o.y = pack_rne((x.z - mu) * inv * gg.z + bb.z, (x.w - mu) * inv * gg.w + bb.w);
    ((uint2*)dst)[tid] = o;
  } else {
    int blk = blockIdx.x - 3 * MROWS;
    int widx = blk >> 10, t = blk & 1023;
    int ti = t >> 5, tj = t & 31;
    const float* W = (widx == 0) ? w0 : (widx == 1) ? w1 : (widx == 2) ? w2 : w3;
    u16* O = wtout + (size_t)widx * DIMC * DIMC;
    int tx = tid & 31, ty = tid >> 5;
    #pragma unroll
    for (int rr = 0; rr < 32; rr += 8)
      tile[ty + rr][tx] = W[(size_t)(ti * 32 + ty + rr) * DIMC + tj * 32 + tx];
    __syncthreads();
    #pragma unroll
    for (int rr = 0; rr < 32; rr += 8)
      O[(size_t)(tj * 32 + ty + rr) * DIMC + ti * 32 + tx] = f2bf(tile[tx][ty + rr]);
  }
}

// ---------------- fused QKV projection GEMM (grid.z selects Q/K/V) ----------------
// z==2 epilogue produces V^T [bh][d][n'] with keys PERMUTED within each 32-block:
// key k (r=k&31, g=(r&15)>>2) -> slot g*8 + (r&3) + (r>=16 ? 4 : 0). This makes the
// attention PV B-operand (P in MFMA k-slot order) exactly the lane-local exp
// results, eliminating the P LDS round-trip there (R1-verified semantics).
__global__ __launch_bounds__(256)
void qkv_gemm(const u16* __restrict__ xn, const u16* __restrict__ wt,
              const float* __restrict__ bq, const float* __restrict__ bk,
              const float* __restrict__ bv,
              float* __restrict__ out, u16* __restrict__ qh,
              u16* __restrict__ khb, u16* __restrict__ vtb) {
  __shared__ u16 smem[128 * 136];           // 34.8 KB; front 16 KB doubles as As/Bs
  u16* As = smem;                            // 128*32
  u16* Bs = smem + 4096;                     // 128*32
  u16* Ls = smem;                            // transpose tile [c][m] stride 136
  const int z = blockIdx.z;
  const u16* A  = xn + (size_t)z * MROWS * DIMC;
  const u16* Bt = wt + (size_t)z * DIMC * DIMC;
  const float* bias = (z == 0) ? bq : (z == 1) ? bk : bv;
  const int bm = blockIdx.x, bn = blockIdx.y;
  const int tid = threadIdx.x;
  const int wave = tid >> 6, lane = tid & 63;
  const int wm = (wave & 1) * 64, wn = (wave >> 1) * 64;
  const int row = lane & 15, quad = lane >> 4;
  const float QSCL = 0.18033688011112042f;  // 0.125 * log2(e)
  f32x4 acc[4][4] = {};
  for (int k0 = 0; k0 < DIMC; k0 += 32) {
    #pragma unroll
    for (int c = 0; c < 2; ++c) {
      int e = c * 2048 + tid * 8;
      int rr = e >> 5, col = e & 31;
      gload_lds16(&A[(size_t)(bm * 128 + rr) * DIMC + k0 + col], &As[e]);
      gload_lds16(&Bt[(size_t)(bn * 128 + rr) * DIMC + k0 + col], &Bs[e]);
    }
    __syncthreads();
    bf16x8 a[4], b[4];
    #pragma unroll
    for (int i = 0; i < 4; ++i)
      a[i] = *(const bf16x8*)(&As[(wm + i * 16 + row) * 32 + quad * 8]);
    #pragma unroll
    for (int j = 0; j < 4; ++j)
      b[j] = *(const bf16x8*)(&Bs[(wn + j * 16 + row) * 32 + quad * 8]);
    #pragma unroll
    for (int i = 0; i < 4; ++i)
      #pragma unroll
      for (int j = 0; j < 4; ++j)
        acc[i][j] = __builtin_amdgcn_mfma_f32_16x16x32_bf16(a[i], b[j], acc[i][j], 0, 0, 0);
    __syncthreads();
  }
  #pragma unroll
  for (int i = 0; i < 4; ++i) {
    #pragma unroll
    for (int j = 0; j < 4; ++j) {
      float val[4];
      #pragma unroll
      for (int r = 0; r < 4; ++r) {
        int m = bm * 128 + wm + i * 16 + quad * 4 + r;
        int c = bn * 128 + wn + j * 16 + row;
        val[r] = acc[i][j][r] + bias[c];
        int b_ = m >> 11, n = m & 2047, h = c >> 6, d = c & 63;
        int bh = b_ * HEADS + h;
        size_t hidx = ((size_t)bh * NSEQ + n) * HD + d;
        if (z == 0) {
          qh[hidx] = f2bf(val[r] * QSCL);   // pre-scaled for attention exp2
        } else {
          out[(size_t)z * MROWS * DIMC + hidx] = val[r];
          if (z == 1) khb[hidx] = f2bf(val[r]);
        }
      }
      if (z == 2) {
        int ct = wn + j * 16 + row;
        int mt = wm + i * 16 + quad * 4;
        u32* L = (u32*)(&Ls[ct * 136 + mt]);
        L[0] = pack_rne(val[0], val[1]);
        L[1] = pack_rne(val[2], val[3]);
      }
    }
  }
  if (z == 2) {
    __syncthreads();
    int b_ = (bm * 128) >> 11;
    int nbase = (bm * 128) & 2047;
    #pragma unroll
    for (int it = 0; it < 8; ++it) {
      int idx = it * 256 + tid;
      int ct = idx >> 4, ch = idx & 15;     // ct = c within tile, ch = 8-m chunk
      uint4 y = *(const uint4*)(&Ls[ct * 136 + ch * 8]);
      int c = bn * 128 + ct;
      int h = c >> 6, d = c & 63;
      size_t rowb = ((size_t)(b_ * HEADS + h) * HD + d) * NSEQ;
      int K0 = nbase + ch * 8;              // 8 consecutive keys, K0 % 8 == 0
      // permuted destination within K0's 32-block (see kernel comment)
      int d1 = (K0 & ~31) + ((K0 & 8) ? 16 : 0) + ((K0 & 16) ? 4 : 0);
      uint2 lo; lo.x = y.x; lo.y = y.y;     // keys K0..K0+3  -> slots d1..d1+3
      uint2 hi; hi.x = y.z; hi.y = y.w;     // keys K0+4..K0+7-> slots d1+8..d1+11
      *(uint2*)(&vtb[rowb + d1])     = lo;
      *(uint2*)(&vtb[rowb + d1 + 8]) = hi;
    }
  }
}

// ---------------- output projection GEMM (64x128 tile, fp32 row-major out) ------
__global__ __launch_bounds__(256)
void out_gemm(const u16* __restrict__ A, const u16* __restrict__ Bt,
              const float* __restrict__ bias, float* __restrict__ outf) {
  __shared__ u16 As[64 * 32];
  __shared__ u16 Bs[128 * 32];
  const int bm = blockIdx.x, bn = blockIdx.y;
  const int tid = threadIdx.x;
  const int wave = tid >> 6, lane = tid & 63;
  const int wm = (wave & 1) * 32, wn = (wave >> 1) * 64;
  const int row = lane & 15, quad = lane >> 4;
  f32x4 acc[2][4] = {};
  for (int k0 = 0; k0 < DIMC; k0 += 32) {
    {
      int e = tid * 8;
      int rr = e >> 5, col = e & 31;
      gload_lds16(&A[(size_t)(bm * 64 + rr) * DIMC + k0 + col], &As[e]);
    }
    #pragma unroll
    for (int c = 0; c < 2; ++c) {
      int e = c * 2048 + tid * 8;
      int rr = e >> 5, col = e & 31;
      gload_lds16(&Bt[(size_t)(bn * 128 + rr) * DIMC + k0 + col], &Bs[e]);
    }
    __syncthreads();
    bf16x8 a[2], b[4];
    #pragma unroll
    for (int i = 0; i < 2; ++i)
      a[i] = *(const bf16x8*)(&As[(wm + i * 16 + row) * 32 + quad * 8]);
    #pragma unroll
    for (int j = 0; j < 4; ++j)
      b[j] = *(const bf16x8*)(&Bs[(wn + j * 16 + row) * 32 + quad * 8]);
    #pragma unroll
    for (int i = 0; i < 2; ++i)
      #pragma unroll
      for (int j = 0; j < 4; ++j)
        acc[i][j] = __builtin_amdgcn_mfma_f32_16x16x32_bf16(a[i], b[j], acc[i][j], 0, 0, 0);
    __syncthreads();
  }
  #pragma unroll
  for (int i = 0; i < 2; ++i)
    #pragma unroll
    for (int j = 0; j < 4; ++j)
      #pragma unroll
      for (int r = 0; r < 4; ++r) {
        int m = bm * 64 + wm + i * 16 + quad * 4 + r;
        int c = bn * 128 + wn + j * 16 + row;
        outf[(size_t)m * DIMC + c] = acc[i][j][r] + bias[c];
      }
}

// ---------------- fused flash attention (128-q blocks, 32 q-rows per wave) ------
// R3 structure (proven 57us): 64-key double-buffered LDS staging, issue-before-
// compute; wave owns TWO 16-q tiles (K/V frags read once, reused). NEW: the P
// LDS round-trip is GONE — vtb's producer-side key permutation means the PV
// B-operand in MFMA k-slot order is exactly the lane-local exp results
// (R1-verified semantics; R4 proved Ps was 100% of the 3.15M bank-conflict
// cycles). V-read pattern is byte-identical to R3's conflict-free swizzle.
// LDS 32KB; no fence; DS pipe now = staging writes + K/V frag reads only.
__global__ __launch_bounds__(256)
void attn_fused(const u16* __restrict__ qh, const u16* __restrict__ kh,
                const u16* __restrict__ vt, u16* __restrict__ ao) {
  __shared__ u16 Ks[2][64 * 64];     // [buf][key][d] chunk-swizzled (8KB each)
  __shared__ u16 Vs[2][64 * 64];     // [buf][d][slot] chunk-swizzled (8KB each)
  const int flat = blockIdx.x;
  const int bh = (flat & 7) * 4 + ((flat >> 3) & 3);
  const int qtile = flat >> 5;       // 0..15, 128 q-rows each
  const int b = bh >> 4, h = bh & 15;
  const int tid = threadIdx.x;
  const int wave = tid >> 6, lane = tid & 63;
  const int qi = lane & 15, quad = lane >> 4;
  const int sw = qi & 7;
  const size_t base = (size_t)bh * NSEQ * HD;
  bf16x8 qf[2][2];                   // [q-subtile][d-half]
  #pragma unroll
  for (int qt = 0; qt < 2; ++qt) {
    int qrow = qtile * 128 + wave * 32 + qt * 16 + qi;
    #pragma unroll
    for (int dh = 0; dh < 2; ++dh)
      qf[qt][dh] = *(const bf16x8*)(&qh[base + (size_t)qrow * HD + dh * 32 + quad * 8]);
  }
  // prologue: stage chunk 0 into buffer 0
  #pragma unroll
  for (int c = 0; c < 2; ++c) {
    int p = c * 256 + tid;            // 0..511
    int rk = p >> 3, ck = p & 7;
    gload_lds16(&kh[base + (size_t)rk * HD + (ck ^ (rk & 7)) * 8], &Ks[0][p * 8]);
    gload_lds16(&vt[base + (size_t)rk * NSEQ + (ck ^ (rk & 7)) * 8], &Vs[0][p * 8]);
  }
  __syncthreads();                    // drains vmcnt -> chunk 0 resident
  float li0 = 0.f, li1 = 0.f;
  f32x4 oacc[2][4] = {};
  for (int t = 0; t < NSEQ / 64; ++t) {
    const int cur = t & 1;
    if (t < NSEQ / 64 - 1) {          // issue next chunk's loads BEFORE compute
      #pragma unroll
      for (int c = 0; c < 2; ++c) {
        int p = c * 256 + tid;
        int rk = p >> 3, ck = p & 7;
        gload_lds16(&kh[base + (size_t)((t + 1) * 64 + rk) * HD + (ck ^ (rk & 7)) * 8],
                    &Ks[cur ^ 1][p * 8]);
        gload_lds16(&vt[base + (size_t)rk * NSEQ + (t + 1) * 64 + (ck ^ (rk & 7)) * 8],
                    &Vs[cur ^ 1][p * 8]);
      }
    }
    const u16* Kb = &Ks[cur][0];
    const u16* Vb = &Vs[cur][0];
    #pragma unroll
    for (int kc = 0; kc < 2; ++kc) {
      // K fragments for the two 16-key tiles of this 32-key group (read ONCE,
      // reused for both q-subtiles)
      const u16* kr0 = &Kb[((kc * 2) * 16 + qi) * 64];
      const u16* kr1 = &Kb[((kc * 2 + 1) * 16 + qi) * 64];
      bf16x8 ka0 = *(const bf16x8*)(&kr0[(quad ^ sw) * 8]);
      bf16x8 ka1 = *(const bf16x8*)(&kr0[((4 + quad) ^ sw) * 8]);
      bf16x8 kb0 = *(const bf16x8*)(&kr1[(quad ^ sw) * 8]);
      bf16x8 kb1 = *(const bf16x8*)(&kr1[((4 + quad) ^ sw) * 8]);
      f32x4 s00 = {}, s01 = {}, s10 = {}, s11 = {};   // [q-subtile][key-tile]
      __builtin_amdgcn_s_setprio(1);
      s00 = __builtin_amdgcn_mfma_f32_16x16x32_bf16(ka0, qf[0][0], s00, 0, 0, 0);
      s00 = __builtin_amdgcn_mfma_f32_16x16x32_bf16(ka1, qf[0][1], s00, 0, 0, 0);
      s01 = __builtin_amdgcn_mfma_f32_16x16x32_bf16(kb0, qf[0][0], s01, 0, 0, 0);
      s01 = __builtin_amdgcn_mfma_f32_16x16x32_bf16(kb1, qf[0][1], s01, 0, 0, 0);
      s10 = __builtin_amdgcn_mfma_f32_16x16x32_bf16(ka0, qf[1][0], s10, 0, 0, 0);
      s10 = __builtin_amdgcn_mfma_f32_16x16x32_bf16(ka1, qf[1][1], s10, 0, 0, 0);
      s11 = __builtin_amdgcn_mfma_f32_16x16x32_bf16(kb0, qf[1][0], s11, 0, 0, 0);
      s11 = __builtin_amdgcn_mfma_f32_16x16x32_bf16(kb1, qf[1][1], s11, 0, 0, 0);
      __builtin_amdgcn_s_setprio(0);
      float a0 = EXP2(s00[0]), a1 = EXP2(s00[1]), a2 = EXP2(s00[2]), a3 = EXP2(s00[3]);
      float a4 = EXP2(s01[0]), a5 = EXP2(s01[1]), a6 = EXP2(s01[2]), a7 = EXP2(s01[3]);
      float b0 = EXP2(s10[0]), b1 = EXP2(s10[1]), b2 = EXP2(s10[2]), b3 = EXP2(s10[3]);
      float b4 = EXP2(s11[0]), b5 = EXP2(s11[1]), b6 = EXP2(s11[2]), b7 = EXP2(s11[3]);
      li0 += ((a0 + a1) + (a2 + a3)) + ((a4 + a5) + (a6 + a7));
      li1 += ((b0 + b1) + (b2 + b3)) + ((b4 + b5) + (b6 + b7));
      // P operands directly in registers, in MFMA k-slot order
      // (slot quad*8+e -> key kc*32 + quad*4+e (e<4) / 16+quad*4+(e-4); vtb's
      // producer permutation puts V in the SAME slot order -> A/B consistent)
      union { bf16x8 v; u32 u[4]; } pu0, pu1;
      pu0.u[0] = pack_trunc(a0, a1); pu0.u[1] = pack_trunc(a2, a3);
      pu0.u[2] = pack_trunc(a4, a5); pu0.u[3] = pack_trunc(a6, a7);
      pu1.u[0] = pack_trunc(b0, b1); pu1.u[1] = pack_trunc(b2, b3);
      pu1.u[2] = pack_trunc(b4, b5); pu1.u[3] = pack_trunc(b6, b7);
      __builtin_amdgcn_s_setprio(1);
      #pragma unroll
      for (int dt = 0; dt < 4; ++dt) {
        bf16x8 vf = *(const bf16x8*)(&Vb[(dt * 16 + qi) * 64 + ((kc * 4 + quad) ^ sw) * 8]);
        oacc[0][dt] = __builtin_amdgcn_mfma_f32_16x16x32_bf16(vf, pu0.v, oacc[0][dt], 0, 0, 0);
        oacc[1][dt] = __builtin_amdgcn_mfma_f32_16x16x32_bf16(vf, pu1.v, oacc[1][dt], 0, 0, 0);
      }
      __builtin_amdgcn_s_setprio(0);
    }
    __syncthreads();                  // all waves done with buf[cur]; next loads drained
  }
  // deferred cross-lane softmax-denominator reduction (once, not per chunk)
  li0 += __shfl_xor(li0, 16); li0 += __shfl_xor(li0, 32);
  li1 += __shfl_xor(li1, 16); li1 += __shfl_xor(li1, 32);
  #pragma unroll
  for (int qt = 0; qt < 2; ++qt) {
    float inv = 1.0f / (qt == 0 ? li0 : li1);
    int token = b * NSEQ + qtile * 128 + wave * 32 + qt * 16 + qi;
    #pragma unroll
    for (int dt = 0; dt < 4; ++dt) {
      int col = h * 64 + dt * 16 + quad * 4;
      *(u32*)(&ao[(size_t)token * DIMC + col]) =
          pack_rne(oacc[qt][dt][0] * inv, oacc[qt][dt][1] * inv);
      *(u32*)(&ao[(size_t)token * DIMC + col + 2]) =
          pack_rne(oacc[qt][dt][2] * inv, oacc[qt][dt][3] * inv);
    }
  }
}

extern "C" void kernel_launch(void* const* d_in, const int* in_sizes, int n_in,
                              void* d_out, int out_size, void* d_ws, size_t ws_size,
                              hipStream_t stream) {
  const float* q    = (const float*)d_in[0];
  const float* k    = (const float*)d_in[1];
  const float* v    = (const float*)d_in[2];
  const float* gq   = (const float*)d_in[3];
  const float* bqln = (const float*)d_in[4];
  const float* gk   = (const float*)d_in[5];
  const float* bkln = (const float*)d_in[6];
  const float* gv   = (const float*)d_in[7];
  const float* bvln = (const float*)d_in[8];
  const float* Wq   = (const float*)d_in[9];
  const float* bq   = (const float*)d_in[10];
  const float* Wk   = (const float*)d_in[11];
  const float* bk   = (const float*)d_in[12];
  const float* Wv   = (const float*)d_in[13];
  const float* bv   = (const float*)d_in[14];
  const float* Wp   = (const float*)d_in[15];
  const float* bp   = (const float*)d_in[16];
  float* out = (float*)d_out;

  char* ws = (char*)d_ws;
  u16* xn  = (u16*)(ws);                          // 3 x 4096x1024 bf16 (24MB)
  u16* wt  = (u16*)(ws + (size_t)25165824);       // 4 x 1024x1024 bf16 (8MB)
  u16* qh  = (u16*)(ws + (size_t)33554432);       // [bh][n][d] bf16 (pre-scaled)
  u16* khb = (u16*)(ws + (size_t)41943040);       // [bh][n][d] bf16
  u16* ao  = (u16*)(ws + (size_t)50331648);       // [token][1024] bf16
  // V^T lives in the output-0 region of d_out (16.78 MB, exactly fits);
  // out_gemm overwrites it afterwards.
  u16* vtb = (u16*)d_out;                         // [bh][d][n-permuted] bf16

  const size_t WEL = (size_t)DIMC * DIMC;

  prep<<<3 * MROWS + 4096, 256, 0, stream>>>(q, k, v, gq, bqln, gk, bkln, gv, bvln,
                                             Wq, Wk, Wv, Wp, xn, wt);
  qkv_gemm<<<dim3(MROWS / 128, DIMC / 128, 3), 256, 0, stream>>>(
      xn, wt, bq, bk, bv, out, qh, khb, vtb);
  attn_fused<<<dim3((NSEQ / 128) * BATCH * HEADS), 256, 0, stream>>>(qh, khb, vtb, ao);
  out_gemm<<<dim3(MROWS / 64, DIMC / 128), 256, 0, stream>>>(ao, wt + 3 * WEL, bp, out);
}